// Round 1
// baseline (1498.971 us; speedup 1.0000x reference)
//
#include <hip/hip_runtime.h>
#include <hip/hip_bf16.h>

#define B_   2
#define T_   2048
#define C_   1024
#define H_   16
#define DK_  64
#define M_   (B_ * T_)   // 4096
#define N3_  (3 * C_)    // 3072

// ---------------- GEMM tiles ----------------
#define BM  128
#define BN  128
#define BK  16
#define BMP 132   // padded leading dim (float4-aligned rows: 132*4B = 528B = 33*16B)
#define BNP 132

// ============================================================
// Kernel A: qkv = x @ W_qkv + b_qkv ; scatter q->ws, k,v->d_out [B,H,T,DK]
// ============================================================
__global__ __launch_bounds__(256) void qkv_gemm_kernel(
    const float* __restrict__ x,      // [4096,1024]
    const float* __restrict__ Wqkv,   // [1024,3072]
    const float* __restrict__ bqkv,   // [3072]
    float* __restrict__ q_ws,         // [B,H,T,DK]
    float* __restrict__ k_out,        // [B,H,T,DK]
    float* __restrict__ v_out)        // [B,H,T,DK]
{
    __shared__ float As[BK][BMP];   // As[k][m] (transposed)
    __shared__ float Bs[BK][BNP];   // Bs[k][n]

    const int m0 = blockIdx.x * BM;
    const int n0 = blockIdx.y * BN;
    const int t  = threadIdx.x;
    const int tx = t & 15;          // 0..15 (n dir)
    const int ty = t >> 4;          // 0..15 (m dir)

    float acc[8][8];
    #pragma unroll
    for (int i = 0; i < 8; ++i)
        #pragma unroll
        for (int j = 0; j < 8; ++j) acc[i][j] = 0.f;

    const int rowA = t >> 2, kqA = t & 3;     // A staging: float4 along k
    const int rowB = t >> 5, n4B = t & 31;    // B staging: float4 along n

    for (int k0 = 0; k0 < 1024; k0 += BK) {
        __syncthreads();
        // ---- stage A (128 x 16), transposed into As[k][m] ----
        #pragma unroll
        for (int hh = 0; hh < 2; ++hh) {
            float4 f = *(const float4*)(x + (size_t)(m0 + rowA + hh * 64) * 1024 + k0 + kqA * 4);
            int mm = rowA + hh * 64;
            As[kqA * 4 + 0][mm] = f.x;
            As[kqA * 4 + 1][mm] = f.y;
            As[kqA * 4 + 2][mm] = f.z;
            As[kqA * 4 + 3][mm] = f.w;
        }
        // ---- stage B (16 x 128) ----
        #pragma unroll
        for (int hh = 0; hh < 2; ++hh) {
            float4 f = *(const float4*)(Wqkv + (size_t)(k0 + rowB + hh * 8) * N3_ + n0 + n4B * 4);
            *(float4*)&Bs[rowB + hh * 8][n4B * 4] = f;
        }
        __syncthreads();
        // ---- 8x8 microkernel ----
        #pragma unroll
        for (int kk = 0; kk < BK; ++kk) {
            float a[8], bb[8];
            *(float4*)&a[0]  = *(const float4*)&As[kk][ty * 4];
            *(float4*)&a[4]  = *(const float4*)&As[kk][ty * 4 + 64];
            *(float4*)&bb[0] = *(const float4*)&Bs[kk][tx * 4];
            *(float4*)&bb[4] = *(const float4*)&Bs[kk][tx * 4 + 64];
            #pragma unroll
            for (int i = 0; i < 8; ++i)
                #pragma unroll
                for (int j = 0; j < 8; ++j)
                    acc[i][j] = fmaf(a[i], bb[j], acc[i][j]);
        }
    }

    // ---- epilogue: bias + scatter ----
    const int sec   = n0 >> 10;        // 0=q 1=k 2=v (BN=128 divides 1024, uniform per block)
    const int cbase = n0 & 1023;
    float* dst = (sec == 0) ? q_ws : (sec == 1) ? k_out : v_out;

    #pragma unroll
    for (int ri = 0; ri < 8; ++ri) {
        int m  = m0 + ty * 4 + (ri & 3) + (ri >> 2) * 64;
        int bb_ = m >> 11, tt = m & 2047;
        #pragma unroll
        for (int cj = 0; cj < 2; ++cj) {
            int c  = cbase + tx * 4 + cj * 64;   // col within section
            int hh = c >> 6, d = c & 63;
            int nglob = n0 + tx * 4 + cj * 64;
            float4 v;
            v.x = acc[ri][cj * 4 + 0] + bqkv[nglob + 0];
            v.y = acc[ri][cj * 4 + 1] + bqkv[nglob + 1];
            v.z = acc[ri][cj * 4 + 2] + bqkv[nglob + 2];
            v.w = acc[ri][cj * 4 + 3] + bqkv[nglob + 3];
            *(float4*)(dst + ((size_t)(bb_ * H_ + hh) * T_ + tt) * DK_ + d) = v;
        }
    }
}

// ============================================================
// Kernel B: causal flash attention, fp32, thread-per-q-row
// ============================================================
__global__ __launch_bounds__(128) void attn_kernel(
    const float* __restrict__ q_ws,   // [B,H,T,DK]
    const float* __restrict__ k_in,   // [B,H,T,DK]
    const float* __restrict__ v_in,   // [B,H,T,DK]
    float* __restrict__ yatt)         // [B,T,C]  (written at h*64+d)
{
    __shared__ float Ks[64][64];
    __shared__ float Vs[64][64];

    const int bh  = blockIdx.x;            // 0..31
    const int qt  = 15 - blockIdx.y;       // longest q-tiles first (LPT)
    const int tid = threadIdx.x;           // 0..127
    const int row = qt * 128 + tid;        // global t of this q row
    const int bb  = bh >> 4, hh = bh & 15;

    const float* qb = q_ws + (size_t)bh * T_ * DK_;
    const float* Kb = k_in + (size_t)bh * T_ * DK_;
    const float* Vb = v_in + (size_t)bh * T_ * DK_;

    float qr[64];
    {
        const float4* qp = (const float4*)(qb + (size_t)row * DK_);
        #pragma unroll
        for (int d4 = 0; d4 < 16; ++d4) {
            float4 f = qp[d4];
            qr[d4 * 4 + 0] = f.x * 0.125f;   // 1/sqrt(64)
            qr[d4 * 4 + 1] = f.y * 0.125f;
            qr[d4 * 4 + 2] = f.z * 0.125f;
            qr[d4 * 4 + 3] = f.w * 0.125f;
        }
    }
    float o[64];
    #pragma unroll
    for (int d = 0; d < 64; ++d) o[d] = 0.f;
    float mrun = -1e30f, lrun = 0.f;

    const int ntiles = qt * 2 + 2;
    for (int kt = 0; kt < ntiles; ++kt) {
        const int j0 = kt * 64;
        __syncthreads();
        for (int l = tid; l < 1024; l += 128) {    // stage K,V 64x64 tiles
            int j = l >> 4, d4 = l & 15;
            ((float4*)&Ks[j][0])[d4] = ((const float4*)(Kb + (size_t)(j0 + j) * DK_))[d4];
            ((float4*)&Vs[j][0])[d4] = ((const float4*)(Vb + (size_t)(j0 + j) * DK_))[d4];
        }
        __syncthreads();
        if (j0 > row) continue;   // fully-masked tile for this row (barriers stay uniform)

        #pragma unroll 1
        for (int jc = 0; jc < 64; jc += 16) {
            if (j0 + jc > row) break;
            float s[16];
            #pragma unroll
            for (int jj = 0; jj < 16; ++jj) {
                const float4* kp = (const float4*)&Ks[jc + jj][0];
                float a0 = 0.f, a1 = 0.f, a2 = 0.f, a3 = 0.f;  // 4 chains for ILP
                #pragma unroll
                for (int k4 = 0; k4 < 16; ++k4) {
                    float4 kf = kp[k4];
                    a0 = fmaf(qr[k4 * 4 + 0], kf.x, a0);
                    a1 = fmaf(qr[k4 * 4 + 1], kf.y, a1);
                    a2 = fmaf(qr[k4 * 4 + 2], kf.z, a2);
                    a3 = fmaf(qr[k4 * 4 + 3], kf.w, a3);
                }
                float acc = (a0 + a1) + (a2 + a3);
                s[jj] = (j0 + jc + jj <= row) ? acc : -1e30f;
            }
            float cmax = s[0];
            #pragma unroll
            for (int jj = 1; jj < 16; ++jj) cmax = fmaxf(cmax, s[jj]);
            if (cmax > mrun) {                       // rare: only on new running max
                float r = __expf(mrun - cmax);       // exp(-1e30-..) -> 0 on first hit
                lrun *= r;
                #pragma unroll
                for (int d = 0; d < 64; ++d) o[d] *= r;
                mrun = cmax;
            }
            float psum = 0.f;
            #pragma unroll
            for (int jj = 0; jj < 16; ++jj) { s[jj] = __expf(s[jj] - mrun); psum += s[jj]; }
            lrun += psum;
            #pragma unroll
            for (int jj = 0; jj < 16; ++jj) {
                const float4* vp = (const float4*)&Vs[jc + jj][0];
                float p = s[jj];
                #pragma unroll
                for (int d4 = 0; d4 < 16; ++d4) {
                    float4 vf = vp[d4];
                    o[d4 * 4 + 0] = fmaf(p, vf.x, o[d4 * 4 + 0]);
                    o[d4 * 4 + 1] = fmaf(p, vf.y, o[d4 * 4 + 1]);
                    o[d4 * 4 + 2] = fmaf(p, vf.z, o[d4 * 4 + 2]);
                    o[d4 * 4 + 3] = fmaf(p, vf.w, o[d4 * 4 + 3]);
                }
            }
        }
    }

    const float inv = 1.f / lrun;
    float* yo = yatt + ((size_t)(bb * T_ + row)) * C_ + hh * DK_;
    #pragma unroll
    for (int d4 = 0; d4 < 16; ++d4) {
        float4 f;
        f.x = o[d4 * 4 + 0] * inv;
        f.y = o[d4 * 4 + 1] * inv;
        f.z = o[d4 * 4 + 2] * inv;
        f.w = o[d4 * 4 + 3] * inv;
        ((float4*)yo)[d4] = f;
    }
}

// ============================================================
// Kernel C: y = yatt @ W_proj + b_proj
// ============================================================
__global__ __launch_bounds__(256) void proj_gemm_kernel(
    const float* __restrict__ ya,     // [4096,1024]
    const float* __restrict__ Wp,     // [1024,1024]
    const float* __restrict__ bp,     // [1024]
    float* __restrict__ y)            // [4096,1024]
{
    __shared__ float As[BK][BMP];
    __shared__ float Bs[BK][BNP];

    const int m0 = blockIdx.x * BM;
    const int n0 = blockIdx.y * BN;
    const int t  = threadIdx.x;
    const int tx = t & 15;
    const int ty = t >> 4;

    float acc[8][8];
    #pragma unroll
    for (int i = 0; i < 8; ++i)
        #pragma unroll
        for (int j = 0; j < 8; ++j) acc[i][j] = 0.f;

    const int rowA = t >> 2, kqA = t & 3;
    const int rowB = t >> 5, n4B = t & 31;

    for (int k0 = 0; k0 < 1024; k0 += BK) {
        __syncthreads();
        #pragma unroll
        for (int hh = 0; hh < 2; ++hh) {
            float4 f = *(const float4*)(ya + (size_t)(m0 + rowA + hh * 64) * 1024 + k0 + kqA * 4);
            int mm = rowA + hh * 64;
            As[kqA * 4 + 0][mm] = f.x;
            As[kqA * 4 + 1][mm] = f.y;
            As[kqA * 4 + 2][mm] = f.z;
            As[kqA * 4 + 3][mm] = f.w;
        }
        #pragma unroll
        for (int hh = 0; hh < 2; ++hh) {
            float4 f = *(const float4*)(Wp + (size_t)(k0 + rowB + hh * 8) * 1024 + n0 + n4B * 4);
            *(float4*)&Bs[rowB + hh * 8][n4B * 4] = f;
        }
        __syncthreads();
        #pragma unroll
        for (int kk = 0; kk < BK; ++kk) {
            float a[8], bb[8];
            *(float4*)&a[0]  = *(const float4*)&As[kk][ty * 4];
            *(float4*)&a[4]  = *(const float4*)&As[kk][ty * 4 + 64];
            *(float4*)&bb[0] = *(const float4*)&Bs[kk][tx * 4];
            *(float4*)&bb[4] = *(const float4*)&Bs[kk][tx * 4 + 64];
            #pragma unroll
            for (int i = 0; i < 8; ++i)
                #pragma unroll
                for (int j = 0; j < 8; ++j)
                    acc[i][j] = fmaf(a[i], bb[j], acc[i][j]);
        }
    }

    #pragma unroll
    for (int ri = 0; ri < 8; ++ri) {
        int m = m0 + ty * 4 + (ri & 3) + (ri >> 2) * 64;
        #pragma unroll
        for (int cj = 0; cj < 2; ++cj) {
            int n = n0 + tx * 4 + cj * 64;
            float4 v;
            v.x = acc[ri][cj * 4 + 0] + bp[n + 0];
            v.y = acc[ri][cj * 4 + 1] + bp[n + 1];
            v.z = acc[ri][cj * 4 + 2] + bp[n + 2];
            v.w = acc[ri][cj * 4 + 3] + bp[n + 3];
            *(float4*)(y + (size_t)m * 1024 + n) = v;
        }
    }
}

// ============================================================
extern "C" void kernel_launch(void* const* d_in, const int* in_sizes, int n_in,
                              void* d_out, int out_size, void* d_ws, size_t ws_size,
                              hipStream_t stream) {
    const float* x     = (const float*)d_in[0];
    const float* Wqkv  = (const float*)d_in[1];
    const float* bqkv  = (const float*)d_in[2];
    const float* Wproj = (const float*)d_in[3];
    const float* bproj = (const float*)d_in[4];

    float* y     = (float*)d_out;                 // [B,T,C]      4,194,304
    float* k_out = y + (size_t)4194304;           // [B,H,T,DK]   4,194,304
    float* v_out = y + (size_t)8388608;           // [B,H,T,DK]   4,194,304

    float* q_ws = (float*)d_ws;                   // [B,H,T,DK]
    float* yatt = q_ws + (size_t)4194304;         // [B,T,C]

    qkv_gemm_kernel<<<dim3(32, 24), 256, 0, stream>>>(x, Wqkv, bqkv, q_ws, k_out, v_out);
    attn_kernel<<<dim3(32, 16), 128, 0, stream>>>(q_ws, k_out, v_out, yatt);
    proj_gemm_kernel<<<dim3(32, 8), 256, 0, stream>>>(yatt, Wproj, bproj, y);
}

// Round 3
// 664.944 us; speedup vs baseline: 2.2543x; 2.2543x over previous
//
#include <hip/hip_runtime.h>
#include <hip/hip_bf16.h>

#define B_   2
#define T_   2048
#define C_   1024
#define H_   16
#define DK_  64
#define M_   (B_ * T_)   // 4096
#define N3_  (3 * C_)    // 3072

// ---------------- GEMM tiles ----------------
#define BM  128
#define BN  128
#define BK  16
#define BMP 132
#define BNP 132

typedef __bf16 bf16x8 __attribute__((ext_vector_type(8)));
typedef float  f32x4  __attribute__((ext_vector_type(4)));
typedef unsigned short u16;
typedef u16 u16x4 __attribute__((ext_vector_type(4)));

static __device__ __forceinline__ u16 f2bf(float f) {
    unsigned u = __float_as_uint(f);
    u += 0x7fffu + ((u >> 16) & 1u);   // RNE
    return (u16)(u >> 16);
}
static __device__ __forceinline__ float bf2f(u16 h) {
    return __uint_as_float(((unsigned)h) << 16);
}

// ============================================================
// Kernel A: qkv = x @ W_qkv + b_qkv ; scatter q->ws, k,v->d_out [B,H,T,DK]
// ============================================================
__global__ __launch_bounds__(256) void qkv_gemm_kernel(
    const float* __restrict__ x,      // [4096,1024]
    const float* __restrict__ Wqkv,   // [1024,3072]
    const float* __restrict__ bqkv,   // [3072]
    float* __restrict__ q_ws,         // [B,H,T,DK]
    float* __restrict__ k_out,        // [B,H,T,DK]
    float* __restrict__ v_out)        // [B,H,T,DK]
{
    __shared__ float As[BK][BMP];   // As[k][m] (transposed)
    __shared__ float Bs[BK][BNP];   // Bs[k][n]

    const int m0 = blockIdx.x * BM;
    const int n0 = blockIdx.y * BN;
    const int t  = threadIdx.x;
    const int tx = t & 15;
    const int ty = t >> 4;

    float acc[8][8];
    #pragma unroll
    for (int i = 0; i < 8; ++i)
        #pragma unroll
        for (int j = 0; j < 8; ++j) acc[i][j] = 0.f;

    const int rowA = t >> 2, kqA = t & 3;
    const int rowB = t >> 5, n4B = t & 31;

    for (int k0 = 0; k0 < 1024; k0 += BK) {
        __syncthreads();
        #pragma unroll
        for (int hh = 0; hh < 2; ++hh) {
            float4 f = *(const float4*)(x + (size_t)(m0 + rowA + hh * 64) * 1024 + k0 + kqA * 4);
            int mm = rowA + hh * 64;
            As[kqA * 4 + 0][mm] = f.x;
            As[kqA * 4 + 1][mm] = f.y;
            As[kqA * 4 + 2][mm] = f.z;
            As[kqA * 4 + 3][mm] = f.w;
        }
        #pragma unroll
        for (int hh = 0; hh < 2; ++hh) {
            float4 f = *(const float4*)(Wqkv + (size_t)(k0 + rowB + hh * 8) * N3_ + n0 + n4B * 4);
            *(float4*)&Bs[rowB + hh * 8][n4B * 4] = f;
        }
        __syncthreads();
        #pragma unroll
        for (int kk = 0; kk < BK; ++kk) {
            float a[8], bb[8];
            *(float4*)&a[0]  = *(const float4*)&As[kk][ty * 4];
            *(float4*)&a[4]  = *(const float4*)&As[kk][ty * 4 + 64];
            *(float4*)&bb[0] = *(const float4*)&Bs[kk][tx * 4];
            *(float4*)&bb[4] = *(const float4*)&Bs[kk][tx * 4 + 64];
            #pragma unroll
            for (int i = 0; i < 8; ++i)
                #pragma unroll
                for (int j = 0; j < 8; ++j)
                    acc[i][j] = fmaf(a[i], bb[j], acc[i][j]);
        }
    }

    const int sec   = n0 >> 10;        // 0=q 1=k 2=v
    const int cbase = n0 & 1023;
    float* dst = (sec == 0) ? q_ws : (sec == 1) ? k_out : v_out;

    #pragma unroll
    for (int ri = 0; ri < 8; ++ri) {
        int m  = m0 + ty * 4 + (ri & 3) + (ri >> 2) * 64;
        int bb_ = m >> 11, tt = m & 2047;
        #pragma unroll
        for (int cj = 0; cj < 2; ++cj) {
            int c  = cbase + tx * 4 + cj * 64;
            int hh = c >> 6, d = c & 63;
            int nglob = n0 + tx * 4 + cj * 64;
            float4 v;
            v.x = acc[ri][cj * 4 + 0] + bqkv[nglob + 0];
            v.y = acc[ri][cj * 4 + 1] + bqkv[nglob + 1];
            v.z = acc[ri][cj * 4 + 2] + bqkv[nglob + 2];
            v.w = acc[ri][cj * 4 + 3] + bqkv[nglob + 3];
            *(float4*)(dst + ((size_t)(bb_ * H_ + hh) * T_ + tt) * DK_ + d) = v;
        }
    }
}

// ============================================================
// Kernel B: causal flash attention, bf16 hi/lo split MFMA
//   Per block: 4 waves, 64 q rows; KV tiles of 64.
//   S^T = K·Q^T (swapped): lane owns q-col = lane&15.
//   All LDS tiles row-major [64][64] bf16, swizzle byte ^= (row&7)<<4.
// ============================================================
#define QS_H 0
#define QS_L 8192
#define KS_H 16384
#define KS_L 24576
#define VT_H 32768
#define VT_L 40960
#define PS_H 49152
#define PS_L 57344

__global__ __launch_bounds__(256) void attn_mfma_kernel(
    const float* __restrict__ q_ws,   // [B,H,T,DK]
    const float* __restrict__ k_in,   // [B,H,T,DK]
    const float* __restrict__ v_in,   // [B,H,T,DK]
    float* __restrict__ yatt)         // [B,T,C]
{
    __shared__ __align__(16) char lds[65536];

    const int bh   = blockIdx.x;           // 0..31
    const int qt   = 31 - (int)blockIdx.y; // LPT: longest first
    const int qb   = qt * 64;
    const int t    = threadIdx.x;
    const int lane = t & 63;
    const int w    = t >> 6;     // wave 0..3
    const int g    = lane >> 4;  // 0..3
    const int r15  = lane & 15;

    const float* Qb = q_ws + (size_t)bh * T_ * DK_ + (size_t)qb * DK_;
    const float* Kb = k_in + (size_t)bh * T_ * DK_;
    const float* Vb = v_in + (size_t)bh * T_ * DK_;

    // ---- stage Q (64x64) bf16 hi/lo, scaled by 1/sqrt(dk) ----
    #pragma unroll
    for (int di = 0; di < 4; ++di) {
        int fidx = di * 256 + t;        // flat float4 index 0..1023
        int row  = fidx >> 4;           // 0..63
        int c4   = fidx & 15;
        float4 f = ((const float4*)(Qb + (size_t)row * 64))[c4];
        f.x *= 0.125f; f.y *= 0.125f; f.z *= 0.125f; f.w *= 0.125f;
        u16 h0 = f2bf(f.x), h1 = f2bf(f.y), h2 = f2bf(f.z), h3 = f2bf(f.w);
        u16 l0 = f2bf(f.x - bf2f(h0)), l1 = f2bf(f.y - bf2f(h1));
        u16 l2 = f2bf(f.z - bf2f(h2)), l3 = f2bf(f.w - bf2f(h3));
        int off = (row * 128 + c4 * 8) ^ ((row & 7) << 4);
        u16x4 hv = {h0, h1, h2, h3};
        u16x4 lv = {l0, l1, l2, l3};
        *(u16x4*)(lds + QS_H + off) = hv;
        *(u16x4*)(lds + QS_L + off) = lv;
    }
    __syncthreads();

    // ---- hoist Q fragments (B operand of S^T mfma), per d-chunk ----
    bf16x8 qfh[2], qfl[2];
    const int prow = w * 16 + r15;     // this lane's q row within block
    #pragma unroll
    for (int dc = 0; dc < 2; ++dc) {
        int off = (prow * 128 + dc * 64 + g * 16) ^ ((prow & 7) << 4);
        qfh[dc] = *(const bf16x8*)(lds + QS_H + off);
        qfl[dc] = *(const bf16x8*)(lds + QS_L + off);
    }

    f32x4 zero4 = {0.f, 0.f, 0.f, 0.f};
    f32x4 o[4];                         // O^T tiles: rows d (dt*16+..), col q
    o[0] = zero4; o[1] = zero4; o[2] = zero4; o[3] = zero4;
    float mrun = -1e30f, lrun = 0.f;
    const int qglob = qb + w * 16 + r15;

    const int nt = qt + 1;
    for (int kt = 0; kt < nt; ++kt) {
        const int j0 = kt * 64;
        __syncthreads();   // prev tile fully consumed before restage
        // ---- stage K (row-major) and V (transposed) bf16 hi/lo ----
        #pragma unroll
        for (int di = 0; di < 4; ++di) {
            int fidx = di * 256 + t;
            int row  = fidx >> 4;
            int c4   = fidx & 15;
            float4 fk = ((const float4*)(Kb + (size_t)(j0 + row) * 64))[c4];
            u16 h0 = f2bf(fk.x), h1 = f2bf(fk.y), h2 = f2bf(fk.z), h3 = f2bf(fk.w);
            u16 l0 = f2bf(fk.x - bf2f(h0)), l1 = f2bf(fk.y - bf2f(h1));
            u16 l2 = f2bf(fk.z - bf2f(h2)), l3 = f2bf(fk.w - bf2f(h3));
            int off = (row * 128 + c4 * 8) ^ ((row & 7) << 4);
            u16x4 hv = {h0, h1, h2, h3};
            u16x4 lv = {l0, l1, l2, l3};
            *(u16x4*)(lds + KS_H + off) = hv;
            *(u16x4*)(lds + KS_L + off) = lv;

            float4 fv = ((const float4*)(Vb + (size_t)(j0 + row) * 64))[c4];
            float vv[4] = {fv.x, fv.y, fv.z, fv.w};
            #pragma unroll
            for (int j = 0; j < 4; ++j) {
                int jj = (j + t) & 3;          // rotate to spread LDS banks
                float x = vv[jj];
                int dd  = c4 * 4 + jj;
                u16 hh = f2bf(x);
                u16 ll = f2bf(x - bf2f(hh));
                int offv = (dd * 128 + row * 2) ^ ((dd & 7) << 4);
                *(u16*)(lds + VT_H + offv) = hh;
                *(u16*)(lds + VT_L + offv) = ll;
            }
        }
        __syncthreads();

        // ---- S^T = K·Q^T : 4 k-subtiles of 16 ----
        float sv[4][4];
        const bool diag = (kt == qt);
        #pragma unroll
        for (int st = 0; st < 4; ++st) {
            f32x4 acc = zero4;
            int krow = st * 16 + r15;
            #pragma unroll
            for (int dc = 0; dc < 2; ++dc) {
                int off = (krow * 128 + dc * 64 + g * 16) ^ ((krow & 7) << 4);
                bf16x8 kh = *(const bf16x8*)(lds + KS_H + off);
                bf16x8 kl = *(const bf16x8*)(lds + KS_L + off);
                acc = __builtin_amdgcn_mfma_f32_16x16x32_bf16(kh, qfh[dc], acc, 0, 0, 0);
                acc = __builtin_amdgcn_mfma_f32_16x16x32_bf16(kh, qfl[dc], acc, 0, 0, 0);
                acc = __builtin_amdgcn_mfma_f32_16x16x32_bf16(kl, qfh[dc], acc, 0, 0, 0);
            }
            #pragma unroll
            for (int r = 0; r < 4; ++r) {
                float x = acc[r];
                if (diag) {
                    int kg = j0 + st * 16 + g * 4 + r;
                    if (kg > qglob) x = -1e30f;
                }
                sv[st][r] = x;
            }
        }

        // ---- online softmax (per q = lane&15 column) ----
        float tm = sv[0][0];
        #pragma unroll
        for (int st = 0; st < 4; ++st)
            #pragma unroll
            for (int r = 0; r < 4; ++r) tm = fmaxf(tm, sv[st][r]);
        tm = fmaxf(tm, __shfl_xor(tm, 16));
        tm = fmaxf(tm, __shfl_xor(tm, 32));
        float mnew = fmaxf(mrun, tm);
        float resc = __expf(mrun - mnew);
        mrun = mnew;
        lrun *= resc;
        o[0] *= resc; o[1] *= resc; o[2] *= resc; o[3] *= resc;

        float ps = 0.f;
        #pragma unroll
        for (int st = 0; st < 4; ++st)
            #pragma unroll
            for (int r = 0; r < 4; ++r) {
                float p = __expf(sv[st][r] - mnew);
                sv[st][r] = p;
                ps += p;
            }
        ps += __shfl_xor(ps, 16);
        ps += __shfl_xor(ps, 32);
        lrun += ps;

        // ---- write P hi/lo (wave-private rows; b64 packed) ----
        #pragma unroll
        for (int st = 0; st < 4; ++st) {
            u16 h0 = f2bf(sv[st][0]), h1 = f2bf(sv[st][1]);
            u16 h2 = f2bf(sv[st][2]), h3 = f2bf(sv[st][3]);
            u16 l0 = f2bf(sv[st][0] - bf2f(h0)), l1 = f2bf(sv[st][1] - bf2f(h1));
            u16 l2 = f2bf(sv[st][2] - bf2f(h2)), l3 = f2bf(sv[st][3] - bf2f(h3));
            int off = (prow * 128 + (st * 16 + g * 4) * 2) ^ ((prow & 7) << 4);
            u16x4 hv = {h0, h1, h2, h3};
            u16x4 lv = {l0, l1, l2, l3};
            *(u16x4*)(lds + PS_H + off) = hv;
            *(u16x4*)(lds + PS_L + off) = lv;
        }

        // ---- O^T += V^T · P^T ----
        bf16x8 pfh[2], pfl[2];
        #pragma unroll
        for (int kc = 0; kc < 2; ++kc) {
            int off = (prow * 128 + kc * 64 + g * 16) ^ ((prow & 7) << 4);
            pfh[kc] = *(const bf16x8*)(lds + PS_H + off);
            pfl[kc] = *(const bf16x8*)(lds + PS_L + off);
        }
        #pragma unroll
        for (int dt = 0; dt < 4; ++dt) {
            int vrow = dt * 16 + r15;
            #pragma unroll
            for (int kc = 0; kc < 2; ++kc) {
                int off = (vrow * 128 + kc * 64 + g * 16) ^ ((vrow & 7) << 4);
                bf16x8 vh = *(const bf16x8*)(lds + VT_H + off);
                bf16x8 vl = *(const bf16x8*)(lds + VT_L + off);
                o[dt] = __builtin_amdgcn_mfma_f32_16x16x32_bf16(vh, pfh[kc], o[dt], 0, 0, 0);
                o[dt] = __builtin_amdgcn_mfma_f32_16x16x32_bf16(vh, pfl[kc], o[dt], 0, 0, 0);
                o[dt] = __builtin_amdgcn_mfma_f32_16x16x32_bf16(vl, pfh[kc], o[dt], 0, 0, 0);
            }
        }
    }

    // ---- epilogue: O^T[d][q] -> yatt[b][q][h*64+d] ----
    const int b = bh >> 4, h = bh & 15;
    const float inv = 1.f / lrun;
    float* yo = yatt + ((size_t)b * T_ + qglob) * C_ + h * DK_;
    #pragma unroll
    for (int dt = 0; dt < 4; ++dt)
        #pragma unroll
        for (int r = 0; r < 4; ++r)
            yo[dt * 16 + g * 4 + r] = o[dt][r] * inv;
}

// ============================================================
// Kernel C: y = yatt @ W_proj + b_proj
// ============================================================
__global__ __launch_bounds__(256) void proj_gemm_kernel(
    const float* __restrict__ ya,     // [4096,1024]
    const float* __restrict__ Wp,     // [1024,1024]
    const float* __restrict__ bp,     // [1024]
    float* __restrict__ y)            // [4096,1024]
{
    __shared__ float As[BK][BMP];
    __shared__ float Bs[BK][BNP];

    const int m0 = blockIdx.x * BM;
    const int n0 = blockIdx.y * BN;
    const int t  = threadIdx.x;
    const int tx = t & 15;
    const int ty = t >> 4;

    float acc[8][8];
    #pragma unroll
    for (int i = 0; i < 8; ++i)
        #pragma unroll
        for (int j = 0; j < 8; ++j) acc[i][j] = 0.f;

    const int rowA = t >> 2, kqA = t & 3;
    const int rowB = t >> 5, n4B = t & 31;

    for (int k0 = 0; k0 < 1024; k0 += BK) {
        __syncthreads();
        #pragma unroll
        for (int hh = 0; hh < 2; ++hh) {
            float4 f = *(const float4*)(ya + (size_t)(m0 + rowA + hh * 64) * 1024 + k0 + kqA * 4);
            int mm = rowA + hh * 64;
            As[kqA * 4 + 0][mm] = f.x;
            As[kqA * 4 + 1][mm] = f.y;
            As[kqA * 4 + 2][mm] = f.z;
            As[kqA * 4 + 3][mm] = f.w;
        }
        #pragma unroll
        for (int hh = 0; hh < 2; ++hh) {
            float4 f = *(const float4*)(Wp + (size_t)(k0 + rowB + hh * 8) * 1024 + n0 + n4B * 4);
            *(float4*)&Bs[rowB + hh * 8][n4B * 4] = f;
        }
        __syncthreads();
        #pragma unroll
        for (int kk = 0; kk < BK; ++kk) {
            float a[8], bb[8];
            *(float4*)&a[0]  = *(const float4*)&As[kk][ty * 4];
            *(float4*)&a[4]  = *(const float4*)&As[kk][ty * 4 + 64];
            *(float4*)&bb[0] = *(const float4*)&Bs[kk][tx * 4];
            *(float4*)&bb[4] = *(const float4*)&Bs[kk][tx * 4 + 64];
            #pragma unroll
            for (int i = 0; i < 8; ++i)
                #pragma unroll
                for (int j = 0; j < 8; ++j)
                    acc[i][j] = fmaf(a[i], bb[j], acc[i][j]);
        }
    }

    #pragma unroll
    for (int ri = 0; ri < 8; ++ri) {
        int m = m0 + ty * 4 + (ri & 3) + (ri >> 2) * 64;
        #pragma unroll
        for (int cj = 0; cj < 2; ++cj) {
            int n = n0 + tx * 4 + cj * 64;
            float4 v;
            v.x = acc[ri][cj * 4 + 0] + bp[n + 0];
            v.y = acc[ri][cj * 4 + 1] + bp[n + 1];
            v.z = acc[ri][cj * 4 + 2] + bp[n + 2];
            v.w = acc[ri][cj * 4 + 3] + bp[n + 3];
            *(float4*)(y + (size_t)m * 1024 + n) = v;
        }
    }
}

// ============================================================
extern "C" void kernel_launch(void* const* d_in, const int* in_sizes, int n_in,
                              void* d_out, int out_size, void* d_ws, size_t ws_size,
                              hipStream_t stream) {
    const float* x     = (const float*)d_in[0];
    const float* Wqkv  = (const float*)d_in[1];
    const float* bqkv  = (const float*)d_in[2];
    const float* Wproj = (const float*)d_in[3];
    const float* bproj = (const float*)d_in[4];

    float* y     = (float*)d_out;                 // [B,T,C]
    float* k_out = y + (size_t)4194304;           // [B,H,T,DK]
    float* v_out = y + (size_t)8388608;           // [B,H,T,DK]

    float* q_ws = (float*)d_ws;                   // [B,H,T,DK]
    float* yatt = q_ws + (size_t)4194304;         // [B,T,C]

    qkv_gemm_kernel<<<dim3(32, 24), 256, 0, stream>>>(x, Wqkv, bqkv, q_ws, k_out, v_out);
    attn_mfma_kernel<<<dim3(32, 32), 256, 0, stream>>>(q_ws, k_out, v_out, yatt);
    proj_gemm_kernel<<<dim3(32, 8), 256, 0, stream>>>(yatt, Wproj, bproj, y);
}

// Round 6
// 341.223 us; speedup vs baseline: 4.3929x; 1.9487x over previous
//
#include <hip/hip_runtime.h>
#include <hip/hip_bf16.h>

#define B_   2
#define T_   2048
#define C_   1024
#define H_   16
#define DK_  64

typedef __bf16 bf16x8 __attribute__((ext_vector_type(8)));
typedef float  f32x4  __attribute__((ext_vector_type(4)));
typedef unsigned short u16;
typedef u16 u16x4 __attribute__((ext_vector_type(4)));
typedef u16 u16x8 __attribute__((ext_vector_type(8)));

static __device__ __forceinline__ u16 f2bf(float f) {
    unsigned u = __float_as_uint(f);
    u += 0x7fffu + ((u >> 16) & 1u);   // RNE
    return (u16)(u >> 16);
}
static __device__ __forceinline__ float bf2f(u16 h) {
    return __uint_as_float(((unsigned)h) << 16);
}

// async global->LDS 16B: LDS dest is wave-uniform base + lane*16; global src per-lane
static __device__ __forceinline__ void async16(void* l, const void* g) {
    __builtin_amdgcn_global_load_lds(
        (const __attribute__((address_space(1))) unsigned int*)g,
        (__attribute__((address_space(3))) unsigned int*)l, 16, 0, 0);
}

// ============================================================
// pack_a_hl: fp32 [4096][1024] -> tiles [mt][kt32][128 rows x (hi64B|lo64B)], swizzled
// ============================================================
__global__ __launch_bounds__(256) void pack_a_hl(const float* __restrict__ src, char* __restrict__ dst) {
    const int mt = blockIdx.x, kt = blockIdx.y, t = threadIdx.x;
    const int r = t >> 1, half = t & 1;
    const float* s = src + (size_t)(mt * 128 + r) * 1024 + kt * 32 + half * 16;
    float f[16];
    #pragma unroll
    for (int i = 0; i < 4; ++i) *(float4*)&f[i * 4] = ((const float4*)s)[i];
    u16 hi[16] __attribute__((aligned(16))), lo[16] __attribute__((aligned(16)));
    #pragma unroll
    for (int e = 0; e < 16; ++e) { hi[e] = f2bf(f[e]); lo[e] = f2bf(f[e] - bf2f(hi[e])); }
    char* tb = dst + ((size_t)mt * 32 + kt) * 16384;
    const int sw = (r & 7) << 4;
    #pragma unroll
    for (int j = 0; j < 2; ++j) {
        int g = half * 2 + j;
        *(u16x8*)(tb + ((r * 128 + g * 16) ^ sw))      = *(u16x8*)&hi[j * 8];
        *(u16x8*)(tb + ((r * 128 + 64 + g * 16) ^ sw)) = *(u16x8*)&lo[j * 8];
    }
}

// ============================================================
// pack_a_s: fp32 [4096][1024] -> tiles [mt][kt64][128 rows x 128B single-bf16], swizzled
// ============================================================
__global__ __launch_bounds__(256) void pack_a_s(const float* __restrict__ src, char* __restrict__ dst) {
    const int mt = blockIdx.x, kt = blockIdx.y, t = threadIdx.x;
    const int r = t >> 1, half = t & 1;
    const float* s = src + (size_t)(mt * 128 + r) * 1024 + kt * 64 + half * 32;
    float f[32];
    #pragma unroll
    for (int i = 0; i < 8; ++i) *(float4*)&f[i * 4] = ((const float4*)s)[i];
    u16 hv[32] __attribute__((aligned(16)));
    #pragma unroll
    for (int e = 0; e < 32; ++e) hv[e] = f2bf(f[e]);
    char* tb = dst + ((size_t)mt * 16 + kt) * 16384;
    const int sw = (r & 7) << 4;
    #pragma unroll
    for (int j = 0; j < 4; ++j) {
        int g = half * 4 + j;
        *(u16x8*)(tb + ((r * 128 + g * 16) ^ sw)) = *(u16x8*)&hv[j * 8];
    }
}

// ============================================================
// pack_bt_hl<BKT>: W [K][N] fp32 -> transposed tiles
//   [nt][kt][128 n-rows x (hi BKT*2B | lo BKT*2B)], swizzled. LDS transpose.
// ============================================================
template <int BKT>
__global__ __launch_bounds__(256) void pack_bt_hl(const float* __restrict__ W, char* __restrict__ dst,
                                                  int N, int nkt) {
    __shared__ float Ls[BKT][132];
    const int nt = blockIdx.x, kt = blockIdx.y, t = threadIdx.x;
    #pragma unroll
    for (int p = 0; p < BKT / 32; ++p) {
        int kr = p * 32 + (t >> 3), c8 = t & 7;
        const float* s = W + (size_t)(kt * BKT + kr) * N + nt * 128 + c8 * 16;
        #pragma unroll
        for (int i = 0; i < 4; ++i) *(float4*)&Ls[kr][c8 * 16 + i * 4] = ((const float4*)s)[i];
    }
    __syncthreads();
    const int nr = t >> 1, half = t & 1;
    constexpr int KH = BKT / 2;
    constexpr int ROWB = BKT * 4;          // 128 or 256
    constexpr int TILEB = 128 * ROWB;      // 16384 or 32768
    char* tb = dst + ((size_t)nt * nkt + kt) * TILEB;
    u16 hi[KH] __attribute__((aligned(16))), lo[KH] __attribute__((aligned(16)));
    #pragma unroll
    for (int e = 0; e < KH; ++e) {
        float x = Ls[half * KH + e][nr];
        hi[e] = f2bf(x); lo[e] = f2bf(x - bf2f(hi[e]));
    }
    const int sw = (nr & 7) << 4;
    #pragma unroll
    for (int j = 0; j < KH / 8; ++j) {
        int g = half * (KH / 8) + j;
        *(u16x8*)(tb + ((nr * ROWB + g * 16) ^ sw))            = *(u16x8*)&hi[j * 8];
        *(u16x8*)(tb + ((nr * ROWB + ROWB / 2 + g * 16) ^ sw)) = *(u16x8*)&lo[j * 8];
    }
}

// ============================================================
// qkv GEMM: C = A(hi/lo) x B(hi/lo), 3-product. 128x128 tile, BK=32, 4 waves.
// ============================================================
__global__ __launch_bounds__(256, 2) void qkv_gemm_bf16(
    const char* __restrict__ xp, const char* __restrict__ wqp,
    const float* __restrict__ bqkv,
    float* __restrict__ qy, float* __restrict__ k_out, float* __restrict__ v_out)
{
    __shared__ __align__(16) char Alds[16384];
    __shared__ __align__(16) char Blds[16384];
    const int mt = blockIdx.x, nt = blockIdx.y;
    const int t = threadIdx.x, lane = t & 63, w = t >> 6;
    const int g = lane >> 4, r15 = lane & 15;
    const int wm = w >> 1, wn = w & 1;

    int aoff[4][2], boff[4][2];
    #pragma unroll
    for (int s = 0; s < 4; ++s) {
        int ar = wm * 64 + s * 16 + r15, sa = (ar & 7) << 4;
        aoff[s][0] = (ar * 128 + g * 16) ^ sa;
        aoff[s][1] = (ar * 128 + 64 + g * 16) ^ sa;
        int br = wn * 64 + s * 16 + r15, sb = (br & 7) << 4;
        boff[s][0] = (br * 128 + g * 16) ^ sb;
        boff[s][1] = (br * 128 + 64 + g * 16) ^ sb;
    }

    f32x4 acc[4][4];
    #pragma unroll
    for (int i = 0; i < 4; ++i)
        #pragma unroll
        for (int j = 0; j < 4; ++j) acc[i][j] = (f32x4){0.f, 0.f, 0.f, 0.f};

    const char* Abase = xp + (size_t)mt * 32 * 16384 + w * 4096 + lane * 16;
    const char* Bbase = wqp + (size_t)nt * 32 * 16384 + w * 4096 + lane * 16;
    char* la = Alds + w * 4096;
    char* lb = Blds + w * 4096;

    for (int kt = 0; kt < 32; ++kt) {
        #pragma unroll
        for (int i = 0; i < 4; ++i) {
            async16(la + i * 1024, Abase + kt * 16384 + i * 1024);
            async16(lb + i * 1024, Bbase + kt * 16384 + i * 1024);
        }
        __syncthreads();
        bf16x8 af[4][2], bf[4][2];
        #pragma unroll
        for (int s = 0; s < 4; ++s) {
            af[s][0] = *(const bf16x8*)(Alds + aoff[s][0]);
            af[s][1] = *(const bf16x8*)(Alds + aoff[s][1]);
            bf[s][0] = *(const bf16x8*)(Blds + boff[s][0]);
            bf[s][1] = *(const bf16x8*)(Blds + boff[s][1]);
        }
        #pragma unroll
        for (int i = 0; i < 4; ++i)
            #pragma unroll
            for (int j = 0; j < 4; ++j) {
                acc[i][j] = __builtin_amdgcn_mfma_f32_16x16x32_bf16(af[i][0], bf[j][0], acc[i][j], 0, 0, 0);
                acc[i][j] = __builtin_amdgcn_mfma_f32_16x16x32_bf16(af[i][0], bf[j][1], acc[i][j], 0, 0, 0);
                acc[i][j] = __builtin_amdgcn_mfma_f32_16x16x32_bf16(af[i][1], bf[j][0], acc[i][j], 0, 0, 0);
            }
        __syncthreads();
    }

    const int n0 = nt * 128;
    const int sec = n0 >> 10;                 // 0=q 1=k 2=v (uniform per block)
    float* kv = (sec == 1) ? k_out : v_out;
    #pragma unroll
    for (int i = 0; i < 4; ++i) {
        int mbase = mt * 128 + wm * 64 + i * 16 + g * 4;
        #pragma unroll
        for (int j = 0; j < 4; ++j) {
            int n = n0 + wn * 64 + j * 16 + r15;
            float bias = bqkv[n];
            int c = n & 1023;
            #pragma unroll
            for (int r = 0; r < 4; ++r) {
                int m = mbase + r;
                int bb = m >> 11, tt = m & 2047;
                float val = acc[i][j][r] + bias;
                if (sec == 0)
                    qy[((size_t)bb * T_ + tt) * C_ + c] = val;
                else
                    kv[(((size_t)bb * H_ + (c >> 6)) * T_ + tt) * DK_ + (c & 63)] = val;
            }
        }
    }
}

// ============================================================
// proj GEMM: C = A(single bf16) x B(hi/lo), 2-product. BK=64, 4 waves.
// ============================================================
__global__ __launch_bounds__(256, 2) void proj_gemm_bf16(
    const char* __restrict__ yap, const char* __restrict__ wpp,
    const float* __restrict__ bp, float* __restrict__ y)
{
    __shared__ __align__(16) char Alds[16384];
    __shared__ __align__(16) char Blds[32768];
    const int mt = blockIdx.x, nt = blockIdx.y;
    const int t = threadIdx.x, lane = t & 63, w = t >> 6;
    const int g = lane >> 4, r15 = lane & 15;
    const int wm = w >> 1, wn = w & 1;

    int aoff[4][2], boffh[4][2], boffl[4][2];
    #pragma unroll
    for (int s = 0; s < 4; ++s) {
        int ar = wm * 64 + s * 16 + r15, sa = (ar & 7) << 4;
        int br = wn * 64 + s * 16 + r15, sb = (br & 7) << 4;
        #pragma unroll
        for (int kk = 0; kk < 2; ++kk) {
            aoff[s][kk]  = (ar * 128 + (kk * 4 + g) * 16) ^ sa;
            boffh[s][kk] = (br * 256 + (kk * 4 + g) * 16) ^ sb;
            boffl[s][kk] = (br * 256 + 128 + (kk * 4 + g) * 16) ^ sb;
        }
    }

    f32x4 acc[4][4];
    #pragma unroll
    for (int i = 0; i < 4; ++i)
        #pragma unroll
        for (int j = 0; j < 4; ++j) acc[i][j] = (f32x4){0.f, 0.f, 0.f, 0.f};

    const char* Abase = yap + (size_t)mt * 16 * 16384 + w * 4096 + lane * 16;
    const char* Bbase = wpp + (size_t)nt * 16 * 32768 + w * 8192 + lane * 16;
    char* la = Alds + w * 4096;
    char* lb = Blds + w * 8192;

    for (int kt = 0; kt < 16; ++kt) {
        #pragma unroll
        for (int i = 0; i < 4; ++i)
            async16(la + i * 1024, Abase + kt * 16384 + i * 1024);
        #pragma unroll
        for (int i = 0; i < 8; ++i)
            async16(lb + i * 1024, Bbase + kt * 32768 + i * 1024);
        __syncthreads();
        #pragma unroll
        for (int kk = 0; kk < 2; ++kk) {
            bf16x8 af[4], bh[4], bl[4];
            #pragma unroll
            for (int s = 0; s < 4; ++s) {
                af[s] = *(const bf16x8*)(Alds + aoff[s][kk]);
                bh[s] = *(const bf16x8*)(Blds + boffh[s][kk]);
                bl[s] = *(const bf16x8*)(Blds + boffl[s][kk]);
            }
            #pragma unroll
            for (int i = 0; i < 4; ++i)
                #pragma unroll
                for (int j = 0; j < 4; ++j) {
                    acc[i][j] = __builtin_amdgcn_mfma_f32_16x16x32_bf16(af[i], bh[j], acc[i][j], 0, 0, 0);
                    acc[i][j] = __builtin_amdgcn_mfma_f32_16x16x32_bf16(af[i], bl[j], acc[i][j], 0, 0, 0);
                }
        }
        __syncthreads();
    }

    #pragma unroll
    for (int i = 0; i < 4; ++i) {
        int mbase = mt * 128 + wm * 64 + i * 16 + g * 4;
        #pragma unroll
        for (int j = 0; j < 4; ++j) {
            int n = nt * 128 + wn * 64 + j * 16 + r15;
            float bias = bp[n];
            #pragma unroll
            for (int r = 0; r < 4; ++r)
                y[(size_t)(mbase + r) * 1024 + n] = acc[i][j][r] + bias;
        }
    }
}

// ============================================================
// Kernel B: causal flash attention, bf16 hi/lo split MFMA (validated R3)
//   Q now read from [B,T,C] layout (qy); yatt written [B,T,C].
// ============================================================
#define QS_H 0
#define QS_L 8192
#define KS_H 16384
#define KS_L 24576
#define VT_H 32768
#define VT_L 40960
#define PS_H 49152
#define PS_L 57344

__global__ __launch_bounds__(256) void attn_mfma_kernel(
    const float* __restrict__ qy,     // [B,T,C]
    const float* __restrict__ k_in,   // [B,H,T,DK]
    const float* __restrict__ v_in,   // [B,H,T,DK]
    float* __restrict__ yatt)         // [B,T,C]
{
    __shared__ __align__(16) char lds[65536];

    const int bh   = blockIdx.x;           // 0..31
    const int qt   = 31 - (int)blockIdx.y; // LPT: longest first
    const int qb   = qt * 64;
    const int t    = threadIdx.x;
    const int lane = t & 63;
    const int w    = t >> 6;
    const int g    = lane >> 4;
    const int r15  = lane & 15;
    const int b    = bh >> 4, h = bh & 15;

    const float* Qb = qy + ((size_t)b * T_ + qb) * C_ + h * 64;
    const float* Kb = k_in + (size_t)bh * T_ * DK_;
    const float* Vb = v_in + (size_t)bh * T_ * DK_;

    // ---- stage Q (64 rows x 64 d) bf16 hi/lo, scaled by 1/8 ----
    #pragma unroll
    for (int di = 0; di < 4; ++di) {
        int fidx = di * 256 + t;
        int row  = fidx >> 4;
        int c4   = fidx & 15;
        float4 f = ((const float4*)(Qb + (size_t)row * C_))[c4];
        f.x *= 0.125f; f.y *= 0.125f; f.z *= 0.125f; f.w *= 0.125f;
        u16 h0 = f2bf(f.x), h1 = f2bf(f.y), h2 = f2bf(f.z), h3 = f2bf(f.w);
        u16 l0 = f2bf(f.x - bf2f(h0)), l1 = f2bf(f.y - bf2f(h1));
        u16 l2 = f2bf(f.z - bf2f(h2)), l3 = f2bf(f.w - bf2f(h3));
        int off = (row * 128 + c4 * 8) ^ ((row & 7) << 4);
        u16x4 hv = {h0, h1, h2, h3};
        u16x4 lv = {l0, l1, l2, l3};
        *(u16x4*)(lds + QS_H + off) = hv;
        *(u16x4*)(lds + QS_L + off) = lv;
    }
    __syncthreads();

    bf16x8 qfh[2], qfl[2];
    const int prow = w * 16 + r15;
    #pragma unroll
    for (int dc = 0; dc < 2; ++dc) {
        int off = (prow * 128 + dc * 64 + g * 16) ^ ((prow & 7) << 4);
        qfh[dc] = *(const bf16x8*)(lds + QS_H + off);
        qfl[dc] = *(const bf16x8*)(lds + QS_L + off);
    }

    f32x4 zero4 = {0.f, 0.f, 0.f, 0.f};
    f32x4 o[4];
    o[0] = zero4; o[1] = zero4; o[2] = zero4; o[3] = zero4;
    float mrun = -1e30f, lrun = 0.f;
    const int qglob = qb + w * 16 + r15;

    const int nt = qt + 1;
    for (int kt = 0; kt < nt; ++kt) {
        const int j0 = kt * 64;
        __syncthreads();
        #pragma unroll
        for (int di = 0; di < 4; ++di) {
            int fidx = di * 256 + t;
            int row  = fidx >> 4;
            int c4   = fidx & 15;
            float4 fk = ((const float4*)(Kb + (size_t)(j0 + row) * 64))[c4];
            u16 h0 = f2bf(fk.x), h1 = f2bf(fk.y), h2 = f2bf(fk.z), h3 = f2bf(fk.w);
            u16 l0 = f2bf(fk.x - bf2f(h0)), l1 = f2bf(fk.y - bf2f(h1));
            u16 l2 = f2bf(fk.z - bf2f(h2)), l3 = f2bf(fk.w - bf2f(h3));
            int off = (row * 128 + c4 * 8) ^ ((row & 7) << 4);
            u16x4 hv = {h0, h1, h2, h3};
            u16x4 lv = {l0, l1, l2, l3};
            *(u16x4*)(lds + KS_H + off) = hv;
            *(u16x4*)(lds + KS_L + off) = lv;

            float4 fv = ((const float4*)(Vb + (size_t)(j0 + row) * 64))[c4];
            float vv[4] = {fv.x, fv.y, fv.z, fv.w};
            #pragma unroll
            for (int j = 0; j < 4; ++j) {
                int jj = (j + t) & 3;
                float x = vv[jj];
                int dd  = c4 * 4 + jj;
                u16 hh = f2bf(x);
                u16 ll = f2bf(x - bf2f(hh));
                int offv = (dd * 128 + row * 2) ^ ((dd & 7) << 4);
                *(u16*)(lds + VT_H + offv) = hh;
                *(u16*)(lds + VT_L + offv) = ll;
            }
        }
        __syncthreads();

        float sv[4][4];
        const bool diag = (kt == qt);
        #pragma unroll
        for (int st = 0; st < 4; ++st) {
            f32x4 acc = zero4;
            int krow = st * 16 + r15;
            #pragma unroll
            for (int dc = 0; dc < 2; ++dc) {
                int off = (krow * 128 + dc * 64 + g * 16) ^ ((krow & 7) << 4);
                bf16x8 kh = *(const bf16x8*)(lds + KS_H + off);
                bf16x8 kl = *(const bf16x8*)(lds + KS_L + off);
                acc = __builtin_amdgcn_mfma_f32_16x16x32_bf16(kh, qfh[dc], acc, 0, 0, 0);
                acc = __builtin_amdgcn_mfma_f32_16x16x32_bf16(kh, qfl[dc], acc, 0, 0, 0);
                acc = __builtin_amdgcn_mfma_f32_16x16x32_bf16(kl, qfh[dc], acc, 0, 0, 0);
            }
            #pragma unroll
            for (int r = 0; r < 4; ++r) {
                float x = acc[r];
                if (diag) {
                    int kg = j0 + st * 16 + g * 4 + r;
                    if (kg > qglob) x = -1e30f;
                }
                sv[st][r] = x;
            }
        }

        float tm = sv[0][0];
        #pragma unroll
        for (int st = 0; st < 4; ++st)
            #pragma unroll
            for (int r = 0; r < 4; ++r) tm = fmaxf(tm, sv[st][r]);
        tm = fmaxf(tm, __shfl_xor(tm, 16));
        tm = fmaxf(tm, __shfl_xor(tm, 32));
        float mnew = fmaxf(mrun, tm);
        float resc = __expf(mrun - mnew);
        mrun = mnew;
        lrun *= resc;
        o[0] *= resc; o[1] *= resc; o[2] *= resc; o[3] *= resc;

        float ps = 0.f;
        #pragma unroll
        for (int st = 0; st < 4; ++st)
            #pragma unroll
            for (int r = 0; r < 4; ++r) {
                float p = __expf(sv[st][r] - mnew);
                sv[st][r] = p;
                ps += p;
            }
        ps += __shfl_xor(ps, 16);
        ps += __shfl_xor(ps, 32);
        lrun += ps;

        #pragma unroll
        for (int st = 0; st < 4; ++st) {
            u16 h0 = f2bf(sv[st][0]), h1 = f2bf(sv[st][1]);
            u16 h2 = f2bf(sv[st][2]), h3 = f2bf(sv[st][3]);
            u16 l0 = f2bf(sv[st][0] - bf2f(h0)), l1 = f2bf(sv[st][1] - bf2f(h1));
            u16 l2 = f2bf(sv[st][2] - bf2f(h2)), l3 = f2bf(sv[st][3] - bf2f(h3));
            int off = (prow * 128 + (st * 16 + g * 4) * 2) ^ ((prow & 7) << 4);
            u16x4 hv = {h0, h1, h2, h3};
            u16x4 lv = {l0, l1, l2, l3};
            *(u16x4*)(lds + PS_H + off) = hv;
            *(u16x4*)(lds + PS_L + off) = lv;
        }

        bf16x8 pfh[2], pfl[2];
        #pragma unroll
        for (int kc = 0; kc < 2; ++kc) {
            int off = (prow * 128 + kc * 64 + g * 16) ^ ((prow & 7) << 4);
            pfh[kc] = *(const bf16x8*)(lds + PS_H + off);
            pfl[kc] = *(const bf16x8*)(lds + PS_L + off);
        }
        #pragma unroll
        for (int dt = 0; dt < 4; ++dt) {
            int vrow = dt * 16 + r15;
            #pragma unroll
            for (int kc = 0; kc < 2; ++kc) {
                int off = (vrow * 128 + kc * 64 + g * 16) ^ ((vrow & 7) << 4);
                bf16x8 vh = *(const bf16x8*)(lds + VT_H + off);
                bf16x8 vl = *(const bf16x8*)(lds + VT_L + off);
                o[dt] = __builtin_amdgcn_mfma_f32_16x16x32_bf16(vh, pfh[kc], o[dt], 0, 0, 0);
                o[dt] = __builtin_amdgcn_mfma_f32_16x16x32_bf16(vh, pfl[kc], o[dt], 0, 0, 0);
                o[dt] = __builtin_amdgcn_mfma_f32_16x16x32_bf16(vl, pfh[kc], o[dt], 0, 0, 0);
            }
        }
    }

    const float inv = 1.f / lrun;
    float* yo = yatt + ((size_t)b * T_ + qglob) * C_ + h * DK_;
    #pragma unroll
    for (int dt = 0; dt < 4; ++dt)
        #pragma unroll
        for (int r = 0; r < 4; ++r)
            yo[dt * 16 + g * 4 + r] = o[dt][r] * inv;
}

// ============================================================
extern "C" void kernel_launch(void* const* d_in, const int* in_sizes, int n_in,
                              void* d_out, int out_size, void* d_ws, size_t ws_size,
                              hipStream_t stream) {
    const float* x     = (const float*)d_in[0];
    const float* Wqkv  = (const float*)d_in[1];
    const float* bqkv  = (const float*)d_in[2];
    const float* Wproj = (const float*)d_in[3];
    const float* bproj = (const float*)d_in[4];

    float* y     = (float*)d_out;                 // [B,T,C]; scratch q until proj writes it
    float* qy    = y;
    float* k_out = y + (size_t)4194304;           // [B,H,T,DK] (final output)
    float* v_out = y + (size_t)8388608;           // [B,H,T,DK] (final output)

    char*  ws   = (char*)d_ws;                    // 32 MB total, lifetime-aliased:
    char*  xp   = ws;                             // [0,16M): x packed; dead after qkv
    float* yatt = (float*)ws;                     //   then: attn output fp32
    char*  wqp  = ws + ((size_t)16 << 20);        // [16M,28M): Wqkv packed; dead after qkv
    char*  yap  = ws + ((size_t)16 << 20);        //   then: yatt packed (8 MB)
    char*  wpp  = ws + ((size_t)28 << 20);        // [28M,32M): Wproj packed (live throughout)

    pack_a_hl   <<<dim3(32, 32), 256, 0, stream>>>(x, xp);
    pack_bt_hl<32><<<dim3(24, 32), 256, 0, stream>>>(Wqkv, wqp, 3072, 32);
    pack_bt_hl<64><<<dim3(8, 16), 256, 0, stream>>>(Wproj, wpp, 1024, 16);
    qkv_gemm_bf16<<<dim3(32, 24), 256, 0, stream>>>(xp, wqp, bqkv, qy, k_out, v_out);
    attn_mfma_kernel<<<dim3(32, 32), 256, 0, stream>>>(qy, k_out, v_out, yatt);
    pack_a_s    <<<dim3(32, 16), 256, 0, stream>>>(yatt, yap);
    proj_gemm_bf16<<<dim3(32, 8), 256, 0, stream>>>(yap, wpp, bproj, y);
}

// Round 7
// 291.998 us; speedup vs baseline: 5.1335x; 1.1686x over previous
//
#include <hip/hip_runtime.h>
#include <hip/hip_bf16.h>

#define B_   2
#define T_   2048
#define C_   1024
#define H_   16
#define DK_  64

typedef __bf16 bf16x8 __attribute__((ext_vector_type(8)));
typedef float  f32x4  __attribute__((ext_vector_type(4)));
typedef unsigned short u16;
typedef u16 u16x4 __attribute__((ext_vector_type(4)));
typedef u16 u16x8 __attribute__((ext_vector_type(8)));

static __device__ __forceinline__ u16 f2bf(float f) {
    unsigned u = __float_as_uint(f);
    u += 0x7fffu + ((u >> 16) & 1u);   // RNE
    return (u16)(u >> 16);
}
static __device__ __forceinline__ float bf2f(u16 h) {
    return __uint_as_float(((unsigned)h) << 16);
}

// async global->LDS 16B: LDS dest is wave-uniform base + lane*16; global src per-lane
static __device__ __forceinline__ void async16(void* l, const void* g) {
    __builtin_amdgcn_global_load_lds(
        (const __attribute__((address_space(1))) unsigned int*)g,
        (__attribute__((address_space(3))) unsigned int*)l, 16, 0, 0);
}

// ============================================================
// pack_a_hl: fp32 [4096][1024] -> tiles [mt][kt32][128 rows x (hi64B|lo64B)], swizzled
// ============================================================
__global__ __launch_bounds__(256) void pack_a_hl(const float* __restrict__ src, char* __restrict__ dst) {
    const int mt = blockIdx.x, kt = blockIdx.y, t = threadIdx.x;
    const int r = t >> 1, half = t & 1;
    const float* s = src + (size_t)(mt * 128 + r) * 1024 + kt * 32 + half * 16;
    float f[16];
    #pragma unroll
    for (int i = 0; i < 4; ++i) *(float4*)&f[i * 4] = ((const float4*)s)[i];
    u16 hi[16] __attribute__((aligned(16))), lo[16] __attribute__((aligned(16)));
    #pragma unroll
    for (int e = 0; e < 16; ++e) { hi[e] = f2bf(f[e]); lo[e] = f2bf(f[e] - bf2f(hi[e])); }
    char* tb = dst + ((size_t)mt * 32 + kt) * 16384;
    const int sw = (r & 7) << 4;
    #pragma unroll
    for (int j = 0; j < 2; ++j) {
        int g = half * 2 + j;
        *(u16x8*)(tb + ((r * 128 + g * 16) ^ sw))      = *(u16x8*)&hi[j * 8];
        *(u16x8*)(tb + ((r * 128 + 64 + g * 16) ^ sw)) = *(u16x8*)&lo[j * 8];
    }
}

// ============================================================
// pack_a_s: fp32 [4096][1024] -> tiles [mt][kt64][128 rows x 128B single-bf16], swizzled
// ============================================================
__global__ __launch_bounds__(256) void pack_a_s(const float* __restrict__ src, char* __restrict__ dst) {
    const int mt = blockIdx.x, kt = blockIdx.y, t = threadIdx.x;
    const int r = t >> 1, half = t & 1;
    const float* s = src + (size_t)(mt * 128 + r) * 1024 + kt * 64 + half * 32;
    float f[32];
    #pragma unroll
    for (int i = 0; i < 8; ++i) *(float4*)&f[i * 4] = ((const float4*)s)[i];
    u16 hv[32] __attribute__((aligned(16)));
    #pragma unroll
    for (int e = 0; e < 32; ++e) hv[e] = f2bf(f[e]);
    char* tb = dst + ((size_t)mt * 16 + kt) * 16384;
    const int sw = (r & 7) << 4;
    #pragma unroll
    for (int j = 0; j < 4; ++j) {
        int g = half * 4 + j;
        *(u16x8*)(tb + ((r * 128 + g * 16) ^ sw)) = *(u16x8*)&hv[j * 8];
    }
}

// ============================================================
// pack_bt_hl<BKT>: W [K][N] fp32 -> transposed tiles
//   [nt][kt][128 n-rows x (hi BKT*2B | lo BKT*2B)], swizzled. LDS transpose.
// ============================================================
template <int BKT>
__global__ __launch_bounds__(256) void pack_bt_hl(const float* __restrict__ W, char* __restrict__ dst,
                                                  int N, int nkt) {
    __shared__ float Ls[BKT][132];
    const int nt = blockIdx.x, kt = blockIdx.y, t = threadIdx.x;
    #pragma unroll
    for (int p = 0; p < BKT / 32; ++p) {
        int kr = p * 32 + (t >> 3), c8 = t & 7;
        const float* s = W + (size_t)(kt * BKT + kr) * N + nt * 128 + c8 * 16;
        #pragma unroll
        for (int i = 0; i < 4; ++i) *(float4*)&Ls[kr][c8 * 16 + i * 4] = ((const float4*)s)[i];
    }
    __syncthreads();
    const int nr = t >> 1, half = t & 1;
    constexpr int KH = BKT / 2;
    constexpr int ROWB = BKT * 4;          // 128 or 256
    constexpr int TILEB = 128 * ROWB;      // 16384 or 32768
    char* tb = dst + ((size_t)nt * nkt + kt) * TILEB;
    u16 hi[KH] __attribute__((aligned(16))), lo[KH] __attribute__((aligned(16)));
    #pragma unroll
    for (int e = 0; e < KH; ++e) {
        float x = Ls[half * KH + e][nr];
        hi[e] = f2bf(x); lo[e] = f2bf(x - bf2f(hi[e]));
    }
    const int sw = (nr & 7) << 4;
    #pragma unroll
    for (int j = 0; j < KH / 8; ++j) {
        int g = half * (KH / 8) + j;
        *(u16x8*)(tb + ((nr * ROWB + g * 16) ^ sw))            = *(u16x8*)&hi[j * 8];
        *(u16x8*)(tb + ((nr * ROWB + ROWB / 2 + g * 16) ^ sw)) = *(u16x8*)&lo[j * 8];
    }
}

// ============================================================
// kv_pack: k_out/v_out [bh][t][64] fp32 -> per-(bh,kt) 16KB tiles
//   Kp tile: [64 tok-rows x 128B d] hi at [0,8K), lo at [8K,16K), swizzled
//   Vp tile: [64 d-rows x 128B tok] hi/lo, swizzled (transposed via LDS)
//   Byte layout == attention's LDS layout (rule 21: src perm == read perm).
// ============================================================
__global__ __launch_bounds__(256) void kv_pack(
    const float* __restrict__ k_in, const float* __restrict__ v_in,
    char* __restrict__ kp, char* __restrict__ vp)
{
    __shared__ float Ls[64][68];
    const int bh = blockIdx.x, kt = blockIdx.y, t = threadIdx.x;
    const float* Kb = k_in + (size_t)bh * T_ * DK_ + (size_t)kt * 64 * DK_;
    const float* Vb = v_in + (size_t)bh * T_ * DK_ + (size_t)kt * 64 * DK_;
    char* ktb = kp + ((size_t)bh * 32 + kt) * 16384;
    char* vtb = vp + ((size_t)bh * 32 + kt) * 16384;
    const int row = t >> 2, qtr = t & 3;

    // ---- K: row-major hi/lo ----
    {
        float f[16];
        #pragma unroll
        for (int i = 0; i < 4; ++i)
            *(float4*)&f[i * 4] = ((const float4*)(Kb + (size_t)row * 64 + qtr * 16))[i];
        u16 hi[16] __attribute__((aligned(16))), lo[16] __attribute__((aligned(16)));
        #pragma unroll
        for (int e = 0; e < 16; ++e) { hi[e] = f2bf(f[e]); lo[e] = f2bf(f[e] - bf2f(hi[e])); }
        const int sw = (row & 7) << 4;
        *(u16x8*)(ktb + ((row * 128 + qtr * 32) ^ sw))             = *(u16x8*)&hi[0];
        *(u16x8*)(ktb + ((row * 128 + qtr * 32 + 16) ^ sw))        = *(u16x8*)&hi[8];
        *(u16x8*)(ktb + 8192 + ((row * 128 + qtr * 32) ^ sw))      = *(u16x8*)&lo[0];
        *(u16x8*)(ktb + 8192 + ((row * 128 + qtr * 32 + 16) ^ sw)) = *(u16x8*)&lo[8];
    }

    // ---- V: stage fp32 tile, transpose-emit hi/lo ----
    #pragma unroll
    for (int i = 0; i < 4; ++i)
        *(float4*)&Ls[row][qtr * 16 + i * 4] = ((const float4*)(Vb + (size_t)row * 64 + qtr * 16))[i];
    __syncthreads();
    {
        const int dd = t >> 2, tc2 = t & 3;    // d-row, 16-token chunk
        float f[16];
        #pragma unroll
        for (int k = 0; k < 16; ++k) f[k] = Ls[tc2 * 16 + k][dd];
        u16 hi[16] __attribute__((aligned(16))), lo[16] __attribute__((aligned(16)));
        #pragma unroll
        for (int e = 0; e < 16; ++e) { hi[e] = f2bf(f[e]); lo[e] = f2bf(f[e] - bf2f(hi[e])); }
        const int sw = (dd & 7) << 4;
        *(u16x8*)(vtb + ((dd * 128 + tc2 * 32) ^ sw))             = *(u16x8*)&hi[0];
        *(u16x8*)(vtb + ((dd * 128 + tc2 * 32 + 16) ^ sw))        = *(u16x8*)&hi[8];
        *(u16x8*)(vtb + 8192 + ((dd * 128 + tc2 * 32) ^ sw))      = *(u16x8*)&lo[0];
        *(u16x8*)(vtb + 8192 + ((dd * 128 + tc2 * 32 + 16) ^ sw)) = *(u16x8*)&lo[8];
    }
}

// ============================================================
// qkv GEMM: C = A(hi/lo) x B(hi/lo), 3-product. 128x128 tile, BK=32, 4 waves.
// ============================================================
__global__ __launch_bounds__(256, 2) void qkv_gemm_bf16(
    const char* __restrict__ xp, const char* __restrict__ wqp,
    const float* __restrict__ bqkv,
    float* __restrict__ qy, float* __restrict__ k_out, float* __restrict__ v_out)
{
    __shared__ __align__(16) char Alds[16384];
    __shared__ __align__(16) char Blds[16384];
    const int mt = blockIdx.x, nt = blockIdx.y;
    const int t = threadIdx.x, lane = t & 63, w = t >> 6;
    const int g = lane >> 4, r15 = lane & 15;
    const int wm = w >> 1, wn = w & 1;

    int aoff[4][2], boff[4][2];
    #pragma unroll
    for (int s = 0; s < 4; ++s) {
        int ar = wm * 64 + s * 16 + r15, sa = (ar & 7) << 4;
        aoff[s][0] = (ar * 128 + g * 16) ^ sa;
        aoff[s][1] = (ar * 128 + 64 + g * 16) ^ sa;
        int br = wn * 64 + s * 16 + r15, sb = (br & 7) << 4;
        boff[s][0] = (br * 128 + g * 16) ^ sb;
        boff[s][1] = (br * 128 + 64 + g * 16) ^ sb;
    }

    f32x4 acc[4][4];
    #pragma unroll
    for (int i = 0; i < 4; ++i)
        #pragma unroll
        for (int j = 0; j < 4; ++j) acc[i][j] = (f32x4){0.f, 0.f, 0.f, 0.f};

    const char* Abase = xp + (size_t)mt * 32 * 16384 + w * 4096 + lane * 16;
    const char* Bbase = wqp + (size_t)nt * 32 * 16384 + w * 4096 + lane * 16;
    char* la = Alds + w * 4096;
    char* lb = Blds + w * 4096;

    for (int kt = 0; kt < 32; ++kt) {
        #pragma unroll
        for (int i = 0; i < 4; ++i) {
            async16(la + i * 1024, Abase + kt * 16384 + i * 1024);
            async16(lb + i * 1024, Bbase + kt * 16384 + i * 1024);
        }
        __syncthreads();
        bf16x8 af[4][2], bf[4][2];
        #pragma unroll
        for (int s = 0; s < 4; ++s) {
            af[s][0] = *(const bf16x8*)(Alds + aoff[s][0]);
            af[s][1] = *(const bf16x8*)(Alds + aoff[s][1]);
            bf[s][0] = *(const bf16x8*)(Blds + boff[s][0]);
            bf[s][1] = *(const bf16x8*)(Blds + boff[s][1]);
        }
        #pragma unroll
        for (int i = 0; i < 4; ++i)
            #pragma unroll
            for (int j = 0; j < 4; ++j) {
                acc[i][j] = __builtin_amdgcn_mfma_f32_16x16x32_bf16(af[i][0], bf[j][0], acc[i][j], 0, 0, 0);
                acc[i][j] = __builtin_amdgcn_mfma_f32_16x16x32_bf16(af[i][0], bf[j][1], acc[i][j], 0, 0, 0);
                acc[i][j] = __builtin_amdgcn_mfma_f32_16x16x32_bf16(af[i][1], bf[j][0], acc[i][j], 0, 0, 0);
            }
        __syncthreads();
    }

    const int n0 = nt * 128;
    const int sec = n0 >> 10;                 // 0=q 1=k 2=v (uniform per block)
    float* kv = (sec == 1) ? k_out : v_out;
    #pragma unroll
    for (int i = 0; i < 4; ++i) {
        int mbase = mt * 128 + wm * 64 + i * 16 + g * 4;
        #pragma unroll
        for (int j = 0; j < 4; ++j) {
            int n = n0 + wn * 64 + j * 16 + r15;
            float bias = bqkv[n];
            int c = n & 1023;
            #pragma unroll
            for (int r = 0; r < 4; ++r) {
                int m = mbase + r;
                int bb = m >> 11, tt = m & 2047;
                float val = acc[i][j][r] + bias;
                if (sec == 0)
                    qy[((size_t)bb * T_ + tt) * C_ + c] = val;
                else
                    kv[(((size_t)bb * H_ + (c >> 6)) * T_ + tt) * DK_ + (c & 63)] = val;
            }
        }
    }
}

// ============================================================
// proj GEMM: C = A(single bf16) x B(hi/lo), 2-product. BK=64, 4 waves.
// ============================================================
__global__ __launch_bounds__(256, 2) void proj_gemm_bf16(
    const char* __restrict__ yap, const char* __restrict__ wpp,
    const float* __restrict__ bp, float* __restrict__ y)
{
    __shared__ __align__(16) char Alds[16384];
    __shared__ __align__(16) char Blds[32768];
    const int mt = blockIdx.x, nt = blockIdx.y;
    const int t = threadIdx.x, lane = t & 63, w = t >> 6;
    const int g = lane >> 4, r15 = lane & 15;
    const int wm = w >> 1, wn = w & 1;

    int aoff[4][2], boffh[4][2], boffl[4][2];
    #pragma unroll
    for (int s = 0; s < 4; ++s) {
        int ar = wm * 64 + s * 16 + r15, sa = (ar & 7) << 4;
        int br = wn * 64 + s * 16 + r15, sb = (br & 7) << 4;
        #pragma unroll
        for (int kk = 0; kk < 2; ++kk) {
            aoff[s][kk]  = (ar * 128 + (kk * 4 + g) * 16) ^ sa;
            boffh[s][kk] = (br * 256 + (kk * 4 + g) * 16) ^ sb;
            boffl[s][kk] = (br * 256 + 128 + (kk * 4 + g) * 16) ^ sb;
        }
    }

    f32x4 acc[4][4];
    #pragma unroll
    for (int i = 0; i < 4; ++i)
        #pragma unroll
        for (int j = 0; j < 4; ++j) acc[i][j] = (f32x4){0.f, 0.f, 0.f, 0.f};

    const char* Abase = yap + (size_t)mt * 16 * 16384 + w * 4096 + lane * 16;
    const char* Bbase = wpp + (size_t)nt * 16 * 32768 + w * 8192 + lane * 16;
    char* la = Alds + w * 4096;
    char* lb = Blds + w * 8192;

    for (int kt = 0; kt < 16; ++kt) {
        #pragma unroll
        for (int i = 0; i < 4; ++i)
            async16(la + i * 1024, Abase + kt * 16384 + i * 1024);
        #pragma unroll
        for (int i = 0; i < 8; ++i)
            async16(lb + i * 1024, Bbase + kt * 32768 + i * 1024);
        __syncthreads();
        #pragma unroll
        for (int kk = 0; kk < 2; ++kk) {
            bf16x8 af[4], bh[4], bl[4];
            #pragma unroll
            for (int s = 0; s < 4; ++s) {
                af[s] = *(const bf16x8*)(Alds + aoff[s][kk]);
                bh[s] = *(const bf16x8*)(Blds + boffh[s][kk]);
                bl[s] = *(const bf16x8*)(Blds + boffl[s][kk]);
            }
            #pragma unroll
            for (int i = 0; i < 4; ++i)
                #pragma unroll
                for (int j = 0; j < 4; ++j) {
                    acc[i][j] = __builtin_amdgcn_mfma_f32_16x16x32_bf16(af[i], bh[j], acc[i][j], 0, 0, 0);
                    acc[i][j] = __builtin_amdgcn_mfma_f32_16x16x32_bf16(af[i], bl[j], acc[i][j], 0, 0, 0);
                }
        }
        __syncthreads();
    }

    #pragma unroll
    for (int i = 0; i < 4; ++i) {
        int mbase = mt * 128 + wm * 64 + i * 16 + g * 4;
        #pragma unroll
        for (int j = 0; j < 4; ++j) {
            int n = nt * 128 + wn * 64 + j * 16 + r15;
            float bias = bp[n];
            #pragma unroll
            for (int r = 0; r < 4; ++r)
                y[(size_t)(mbase + r) * 1024 + n] = acc[i][j][r] + bias;
        }
    }
}

// ============================================================
// attention: bf16 hi/lo MFMA; K/V pre-packed (zero staging VALU);
//   in-place Q-read / yatt-write on the y region.
//   LDS 48KB: P overlays dead Q-staging region -> 3 blocks/CU.
// ============================================================
#define PS_H 0
#define PS_L 8192
#define KS_H 16384
#define KS_L 24576
#define VT_H 32768
#define VT_L 40960

__global__ __launch_bounds__(256) void attn_mfma_kernel(
    float* qyatt,                     // [B,T,C]: Q in, yatt out (per-cell read-then-write)
    const char* __restrict__ Kp,      // [bh][kt] 16KB tiles
    const char* __restrict__ Vp)      // [bh][kt] 16KB tiles (transposed)
{
    __shared__ __align__(16) char lds[49152];

    const int bh   = blockIdx.x;           // 0..31
    const int qt   = 31 - (int)blockIdx.y; // LPT: longest first
    const int qb   = qt * 64;
    const int t    = threadIdx.x;
    const int lane = t & 63;
    const int w    = t >> 6;
    const int g    = lane >> 4;
    const int r15  = lane & 15;
    const int b    = bh >> 4, h = bh & 15;

    const float* Qb = qyatt + ((size_t)b * T_ + qb) * C_ + h * 64;

    // ---- stage Q (64 rows x 64 d) bf16 hi/lo into PS region (temp), scaled 1/8 ----
    #pragma unroll
    for (int di = 0; di < 4; ++di) {
        int fidx = di * 256 + t;
        int row  = fidx >> 4;
        int c4   = fidx & 15;
        float4 f = ((const float4*)(Qb + (size_t)row * C_))[c4];
        f.x *= 0.125f; f.y *= 0.125f; f.z *= 0.125f; f.w *= 0.125f;
        u16 h0 = f2bf(f.x), h1 = f2bf(f.y), h2 = f2bf(f.z), h3 = f2bf(f.w);
        u16 l0 = f2bf(f.x - bf2f(h0)), l1 = f2bf(f.y - bf2f(h1));
        u16 l2 = f2bf(f.z - bf2f(h2)), l3 = f2bf(f.w - bf2f(h3));
        int off = (row * 128 + c4 * 8) ^ ((row & 7) << 4);
        u16x4 hv = {h0, h1, h2, h3};
        u16x4 lv = {l0, l1, l2, l3};
        *(u16x4*)(lds + PS_H + off) = hv;
        *(u16x4*)(lds + PS_L + off) = lv;
    }
    __syncthreads();

    bf16x8 qfh[2], qfl[2];
    const int prow = w * 16 + r15;
    #pragma unroll
    for (int dc = 0; dc < 2; ++dc) {
        int off = (prow * 128 + dc * 64 + g * 16) ^ ((prow & 7) << 4);
        qfh[dc] = *(const bf16x8*)(lds + PS_H + off);
        qfl[dc] = *(const bf16x8*)(lds + PS_L + off);
    }

    f32x4 zero4 = {0.f, 0.f, 0.f, 0.f};
    f32x4 o[4];
    o[0] = zero4; o[1] = zero4; o[2] = zero4; o[3] = zero4;
    float mrun = -1e30f, lrun = 0.f;
    const int qglob = qb + w * 16 + r15;

    const int nt = qt + 1;
    for (int kt = 0; kt < nt; ++kt) {
        const int j0 = kt * 64;
        __syncthreads();   // prev tile consumed (kt=0: all waves done hoisting Q)
        // ---- stage K,V: linear async global->LDS of pre-packed tiles ----
        {
            const char* Kg = Kp + ((size_t)bh * 32 + kt) * 16384 + w * 4096 + lane * 16;
            const char* Vg = Vp + ((size_t)bh * 32 + kt) * 16384 + w * 4096 + lane * 16;
            char* lk = lds + KS_H + w * 4096;
            char* lv = lds + VT_H + w * 4096;
            #pragma unroll
            for (int i = 0; i < 4; ++i) {
                async16(lk + i * 1024, Kg + i * 1024);
                async16(lv + i * 1024, Vg + i * 1024);
            }
        }
        __syncthreads();

        // ---- S^T = K.Q^T : 4 k-subtiles of 16 ----
        float sv[4][4];
        const bool diag = (kt == qt);
        #pragma unroll
        for (int st = 0; st < 4; ++st) {
            f32x4 acc = zero4;
            int krow = st * 16 + r15;
            #pragma unroll
            for (int dc = 0; dc < 2; ++dc) {
                int off = (krow * 128 + dc * 64 + g * 16) ^ ((krow & 7) << 4);
                bf16x8 kh = *(const bf16x8*)(lds + KS_H + off);
                bf16x8 kl = *(const bf16x8*)(lds + KS_L + off);
                acc = __builtin_amdgcn_mfma_f32_16x16x32_bf16(kh, qfh[dc], acc, 0, 0, 0);
                acc = __builtin_amdgcn_mfma_f32_16x16x32_bf16(kh, qfl[dc], acc, 0, 0, 0);
                acc = __builtin_amdgcn_mfma_f32_16x16x32_bf16(kl, qfh[dc], acc, 0, 0, 0);
            }
            #pragma unroll
            for (int r = 0; r < 4; ++r) {
                float x = acc[r];
                if (diag) {
                    int kg = j0 + st * 16 + g * 4 + r;
                    if (kg > qglob) x = -1e30f;
                }
                sv[st][r] = x;
            }
        }

        // ---- online softmax (per q = lane&15 column) ----
        float tm = sv[0][0];
        #pragma unroll
        for (int st = 0; st < 4; ++st)
            #pragma unroll
            for (int r = 0; r < 4; ++r) tm = fmaxf(tm, sv[st][r]);
        tm = fmaxf(tm, __shfl_xor(tm, 16));
        tm = fmaxf(tm, __shfl_xor(tm, 32));
        float mnew = fmaxf(mrun, tm);
        float resc = __expf(mrun - mnew);
        mrun = mnew;
        lrun *= resc;
        o[0] *= resc; o[1] *= resc; o[2] *= resc; o[3] *= resc;

        float ps = 0.f;
        #pragma unroll
        for (int st = 0; st < 4; ++st)
            #pragma unroll
            for (int r = 0; r < 4; ++r) {
                float p = __expf(sv[st][r] - mnew);
                sv[st][r] = p;
                ps += p;
            }
        ps += __shfl_xor(ps, 16);
        ps += __shfl_xor(ps, 32);
        lrun += ps;

        // ---- write P hi/lo (wave-private rows) ----
        #pragma unroll
        for (int st = 0; st < 4; ++st) {
            u16 h0 = f2bf(sv[st][0]), h1 = f2bf(sv[st][1]);
            u16 h2 = f2bf(sv[st][2]), h3 = f2bf(sv[st][3]);
            u16 l0 = f2bf(sv[st][0] - bf2f(h0)), l1 = f2bf(sv[st][1] - bf2f(h1));
            u16 l2 = f2bf(sv[st][2] - bf2f(h2)), l3 = f2bf(sv[st][3] - bf2f(h3));
            int off = (prow * 128 + (st * 16 + g * 4) * 2) ^ ((prow & 7) << 4);
            u16x4 hv = {h0, h1, h2, h3};
            u16x4 lv = {l0, l1, l2, l3};
            *(u16x4*)(lds + PS_H + off) = hv;
            *(u16x4*)(lds + PS_L + off) = lv;
        }

        // ---- O^T += V^T . P^T ----
        bf16x8 pfh[2], pfl[2];
        #pragma unroll
        for (int kc = 0; kc < 2; ++kc) {
            int off = (prow * 128 + kc * 64 + g * 16) ^ ((prow & 7) << 4);
            pfh[kc] = *(const bf16x8*)(lds + PS_H + off);
            pfl[kc] = *(const bf16x8*)(lds + PS_L + off);
        }
        #pragma unroll
        for (int dt = 0; dt < 4; ++dt) {
            int vrow = dt * 16 + r15;
            #pragma unroll
            for (int kc = 0; kc < 2; ++kc) {
                int off = (vrow * 128 + kc * 64 + g * 16) ^ ((vrow & 7) << 4);
                bf16x8 vh = *(const bf16x8*)(lds + VT_H + off);
                bf16x8 vl = *(const bf16x8*)(lds + VT_L + off);
                o[dt] = __builtin_amdgcn_mfma_f32_16x16x32_bf16(vh, pfh[kc], o[dt], 0, 0, 0);
                o[dt] = __builtin_amdgcn_mfma_f32_16x16x32_bf16(vh, pfl[kc], o[dt], 0, 0, 0);
                o[dt] = __builtin_amdgcn_mfma_f32_16x16x32_bf16(vl, pfh[kc], o[dt], 0, 0, 0);
            }
        }
    }

    // ---- epilogue: O^T[d][q] -> yatt[b][q][h*64+d] (same cell Q was read from) ----
    const float inv = 1.f / lrun;
    float* yo = qyatt + ((size_t)b * T_ + qglob) * C_ + h * DK_;
    #pragma unroll
    for (int dt = 0; dt < 4; ++dt)
        #pragma unroll
        for (int r = 0; r < 4; ++r)
            yo[dt * 16 + g * 4 + r] = o[dt][r] * inv;
}

// ============================================================
extern "C" void kernel_launch(void* const* d_in, const int* in_sizes, int n_in,
                              void* d_out, int out_size, void* d_ws, size_t ws_size,
                              hipStream_t stream) {
    const float* x     = (const float*)d_in[0];
    const float* Wqkv  = (const float*)d_in[1];
    const float* bqkv  = (const float*)d_in[2];
    const float* Wproj = (const float*)d_in[3];
    const float* bproj = (const float*)d_in[4];

    float* y     = (float*)d_out;                 // [B,T,C]: q fp32 -> yatt -> final y
    float* k_out = y + (size_t)4194304;           // [B,H,T,DK] (final output)
    float* v_out = y + (size_t)8388608;           // [B,H,T,DK] (final output)

    char* ws = (char*)d_ws;                       // 32 MB, lifetime-aliased:
    char* xp  = ws;                               // [0,16M)  x packed        (phase 1-2)
    char* wqp = ws + ((size_t)16 << 20);          // [16M,28M) Wqkv packed    (phase 1-2)
    char* Kp  = ws;                               // [0,16M)  K packed        (phase 3-4)
    char* Vp  = ws + ((size_t)16 << 20);          // [16M,32M) V^T packed     (phase 3-4)
    char* yap = ws;                               // [0,8M)   yatt packed     (phase 5-6)
    char* wpp = ws + ((size_t)8 << 20);           // [8M,12M) Wproj packed    (phase 5-6)

    pack_a_hl     <<<dim3(32, 32), 256, 0, stream>>>(x, xp);
    pack_bt_hl<32><<<dim3(24, 32), 256, 0, stream>>>(Wqkv, wqp, 3072, 32);
    qkv_gemm_bf16 <<<dim3(32, 24), 256, 0, stream>>>(xp, wqp, bqkv, y, k_out, v_out);
    kv_pack       <<<dim3(32, 32), 256, 0, stream>>>(k_out, v_out, Kp, Vp);
    attn_mfma_kernel<<<dim3(32, 32), 256, 0, stream>>>(y, Kp, Vp);
    pack_a_s      <<<dim3(32, 16), 256, 0, stream>>>(y, yap);
    pack_bt_hl<64><<<dim3(8, 16), 256, 0, stream>>>(Wproj, wpp, 1024, 16);
    proj_gemm_bf16<<<dim3(32, 8), 256, 0, stream>>>(yap, wpp, bproj, y);
}